// Round 1
// baseline (1259.292 us; speedup 1.0000x reference)
//
#include <hip/hip_runtime.h>

// GCN 2-layer: x[N,12] -> GCNConv(W1[12,128]) -> relu -> GCNConv(W2[128,64]) -> out[N,64]
// deg/norm from col (in-degree + self loop), symmetric norm dinv[row]*dinv[col].

#define IN_CH 12
#define HID 128
#define OUTC 64

__global__ void k_zero(float* __restrict__ p, int n) {
    int i = blockIdx.x * blockDim.x + threadIdx.x;
    if (i < n) p[i] = 0.0f;
}

__global__ void k_deg(const int* __restrict__ col, float* __restrict__ deg, int E) {
    int e = blockIdx.x * blockDim.x + threadIdx.x;
    if (e < E) unsafeAtomicAdd(&deg[col[e]], 1.0f);
}

__global__ void k_dinv(float* __restrict__ deg, int N) {
    int i = blockIdx.x * blockDim.x + threadIdx.x;
    if (i < N) deg[i] = rsqrtf(deg[i] + 1.0f);
}

// h1 = x @ W1 ; out1 = h1*dinv^2 + b1   (block = 256 threads = 2 nodes x 128 ch)
__global__ __launch_bounds__(256) void k_gemm1(
    const float* __restrict__ x, const float* __restrict__ W1,
    const float* __restrict__ b1, const float* __restrict__ dinv,
    float* __restrict__ h1, float* __restrict__ out1, int N) {
    __shared__ float xs[2][IN_CH];
    int ln = threadIdx.x >> 7;   // local node 0..1
    int c  = threadIdx.x & 127;  // channel
    int n  = blockIdx.x * 2 + ln;
    if (threadIdx.x < 2 * IN_CH) {
        int nn = blockIdx.x * 2 + threadIdx.x / IN_CH;
        int k  = threadIdx.x % IN_CH;
        xs[threadIdx.x / IN_CH][k] = (nn < N) ? x[(long long)nn * IN_CH + k] : 0.0f;
    }
    __syncthreads();
    if (n >= N) return;
    float acc = 0.0f;
#pragma unroll
    for (int k = 0; k < IN_CH; ++k)
        acc = fmaf(xs[ln][k], W1[k * HID + c], acc);
    long long idx = (long long)n * HID + c;
    h1[idx] = acc;
    float dv = dinv[n];
    out1[idx] = fmaf(acc, dv * dv, b1[c]);
}

// out1[col] += h1[row] * dinv[row]*dinv[col]   (block = 256 = 2 edges x 128 ch)
__global__ __launch_bounds__(256) void k_scatter1(
    const int* __restrict__ row, const int* __restrict__ col,
    const float* __restrict__ dinv, const float* __restrict__ h1,
    float* __restrict__ out1, int E) {
    int le = threadIdx.x >> 7;
    int c  = threadIdx.x & 127;
    long long e = (long long)blockIdx.x * 2 + le;
    if (e >= E) return;
    int r  = row[e];
    int cc = col[e];
    float norm = dinv[r] * dinv[cc];
    float v = h1[(long long)r * HID + c] * norm;
    unsafeAtomicAdd(&out1[(long long)cc * HID + c], v);
}

// h2 = relu(out1) @ W2 ; out2 = h2*dinv^2 + b2  (block = 256 = 4 nodes x 64 ch)
__global__ __launch_bounds__(256) void k_gemm2(
    const float* __restrict__ out1, const float* __restrict__ W2,
    const float* __restrict__ b2, const float* __restrict__ dinv,
    float* __restrict__ h2, float* __restrict__ out2, int N) {
    __shared__ float w2s[HID * OUTC];  // 32 KiB
    __shared__ float rows[4][HID];     // 2 KiB
    for (int i = threadIdx.x; i < HID * OUTC; i += 256) w2s[i] = W2[i];
    int ln = threadIdx.x >> 6;  // 0..3
    int c  = threadIdx.x & 63;
    long long n = (long long)blockIdx.x * 4 + ln;
    if (n < N) {
        rows[ln][c]      = fmaxf(out1[n * HID + c], 0.0f);
        rows[ln][c + 64] = fmaxf(out1[n * HID + c + 64], 0.0f);
    }
    __syncthreads();
    if (n >= N) return;
    float acc = 0.0f;
#pragma unroll 8
    for (int k = 0; k < HID; ++k)
        acc = fmaf(rows[ln][k], w2s[k * OUTC + c], acc);
    long long idx = n * OUTC + c;
    h2[idx] = acc;
    float dv = dinv[n];
    out2[idx] = fmaf(acc, dv * dv, b2[c]);
}

// out[col] += h2[row] * norm   (block = 256 = 4 edges x 64 ch)
__global__ __launch_bounds__(256) void k_scatter2(
    const int* __restrict__ row, const int* __restrict__ col,
    const float* __restrict__ dinv, const float* __restrict__ h2,
    float* __restrict__ out, int E) {
    int le = threadIdx.x >> 6;
    int c  = threadIdx.x & 63;
    long long e = (long long)blockIdx.x * 4 + le;
    if (e >= E) return;
    int r  = row[e];
    int cc = col[e];
    float norm = dinv[r] * dinv[cc];
    float v = h2[(long long)r * OUTC + c] * norm;
    unsafeAtomicAdd(&out[(long long)cc * OUTC + c], v);
}

extern "C" void kernel_launch(void* const* d_in, const int* in_sizes, int n_in,
                              void* d_out, int out_size, void* d_ws, size_t ws_size,
                              hipStream_t stream) {
    const float* x  = (const float*)d_in[0];
    const int*   ei = (const int*)d_in[1];
    const float* W1 = (const float*)d_in[2];
    const float* b1 = (const float*)d_in[3];
    const float* W2 = (const float*)d_in[4];
    const float* b2 = (const float*)d_in[5];
    float* out = (float*)d_out;

    const int N = in_sizes[0] / IN_CH;
    const int E = in_sizes[1] / 2;
    const int* row = ei;
    const int* col = ei + E;

    char* ws = (char*)d_ws;
    size_t degBytes = ((size_t)N * 4 + 255) & ~(size_t)255;
    float* deg  = (float*)ws;                        // N floats -> becomes dinv in place
    float* h1   = (float*)(ws + degBytes);           // N*128 floats
    float* out1 = h1 + (size_t)N * HID;              // N*128 floats
    float* h2   = h1;                                // reuse h1 buffer (N*64 <= N*128)

    k_zero<<<(N + 255) / 256, 256, 0, stream>>>(deg, N);
    k_deg<<<(E + 255) / 256, 256, 0, stream>>>(col, deg, E);
    k_dinv<<<(N + 255) / 256, 256, 0, stream>>>(deg, N);
    const float* dinv = deg;

    k_gemm1<<<(N + 1) / 2, 256, 0, stream>>>(x, W1, b1, dinv, h1, out1, N);
    k_scatter1<<<(E + 1) / 2, 256, 0, stream>>>(row, col, dinv, h1, out1, E);
    k_gemm2<<<(N + 3) / 4, 256, 0, stream>>>(out1, W2, b2, dinv, h2, out, N);
    k_scatter2<<<(E + 3) / 4, 256, 0, stream>>>(row, col, dinv, h2, out, E);
}

// Round 2
// 824.526 us; speedup vs baseline: 1.5273x; 1.5273x over previous
//
#include <hip/hip_runtime.h>

// 2-layer GCN, CSR-gather formulation (no float atomics).
// Graph is shared by both layers: build dest-sorted CSR once, gather twice.

#define IN_CH 12
#define HID 128
#define OUTC 64

__global__ void k_zero_i(int* __restrict__ p, int n) {
    int i = blockIdx.x * blockDim.x + threadIdx.x;
    if (i < n) p[i] = 0;
}

__global__ void k_count(const int* __restrict__ col, int* __restrict__ cnt, int E) {
    int e = blockIdx.x * blockDim.x + threadIdx.x;
    if (e < E) atomicAdd(&cnt[col[e]], 1);
}

// dinv[i] = rsqrt(cnt[i]+1); start[i] = running offset (block-scan + one atomic per block)
__global__ __launch_bounds__(256) void k_alloc(
    const int* __restrict__ cnt, float* __restrict__ dinv,
    int* __restrict__ start, int* __restrict__ total, int N) {
    __shared__ int sdata[256];
    __shared__ int sbase;
    int i = blockIdx.x * 256 + threadIdx.x;
    int v = (i < N) ? cnt[i] : 0;
    if (i < N) dinv[i] = rsqrtf((float)v + 1.0f);
    sdata[threadIdx.x] = v;
    __syncthreads();
#pragma unroll
    for (int off = 1; off < 256; off <<= 1) {
        int t = (threadIdx.x >= off) ? sdata[threadIdx.x - off] : 0;
        __syncthreads();
        sdata[threadIdx.x] += t;
        __syncthreads();
    }
    if (threadIdx.x == 255) sbase = atomicAdd(total, sdata[255]);
    __syncthreads();
    if (i < N) start[i] = sbase + sdata[threadIdx.x] - v;  // exclusive scan
}

// edges[start[col]+k] = {row, norm}  (norm precomputed once, reused by both layers)
__global__ void k_fill(const int* __restrict__ row, const int* __restrict__ col,
                       const float* __restrict__ dinv, const int* __restrict__ start,
                       int* __restrict__ cur, int2* __restrict__ edges, int E) {
    int e = blockIdx.x * blockDim.x + threadIdx.x;
    if (e >= E) return;
    int r = row[e], c = col[e];
    int p = start[c] + atomicAdd(&cur[c], 1);
    float nrm = dinv[r] * dinv[c];
    edges[p] = make_int2(r, __float_as_int(nrm));
}

// h1 = x @ W1   (block = 256 threads = 2 nodes x 128 ch)
__global__ __launch_bounds__(256) void k_gemm1(
    const float* __restrict__ x, const float* __restrict__ W1,
    float* __restrict__ h1, int N) {
    __shared__ float xs[2][IN_CH];
    int ln = threadIdx.x >> 7;
    int c  = threadIdx.x & 127;
    int n  = blockIdx.x * 2 + ln;
    if (threadIdx.x < 2 * IN_CH) {
        int nn = blockIdx.x * 2 + threadIdx.x / IN_CH;
        int k  = threadIdx.x % IN_CH;
        xs[threadIdx.x / IN_CH][k] = (nn < N) ? x[(long long)nn * IN_CH + k] : 0.0f;
    }
    __syncthreads();
    if (n >= N) return;
    float acc = 0.0f;
#pragma unroll
    for (int k = 0; k < IN_CH; ++k)
        acc = fmaf(xs[ln][k], W1[k * HID + c], acc);
    h1[(long long)n * HID + c] = acc;
}

// out1 = relu( sum_{e->n} h1[row_e]*norm_e + h1[n]*dinv^2 + b1 )
// block = 256 = 4 waves; wave = 1 node, lane = channel-pair (float2)
__global__ __launch_bounds__(256) void k_gather1(
    const int* __restrict__ start, const int* __restrict__ cnt,
    const float* __restrict__ dinv, const int2* __restrict__ edges,
    const float* __restrict__ h1, const float* __restrict__ b1,
    float* __restrict__ out1, int N) {
    int ln = threadIdx.x >> 6;
    int c  = threadIdx.x & 63;
    int n  = blockIdx.x * 4 + ln;
    if (n >= N) return;
    float dv = dinv[n];
    float2 hv = *(const float2*)(h1 + (size_t)n * HID + 2 * c);
    float2 bb = *(const float2*)(b1 + 2 * c);
    float s = dv * dv;
    float ax = fmaf(hv.x, s, bb.x);
    float ay = fmaf(hv.y, s, bb.y);
    int s0 = start[n], k = cnt[n];
#pragma unroll 4
    for (int j = 0; j < k; ++j) {
        int2 e = edges[s0 + j];                 // wave-uniform broadcast load
        float nrm = __int_as_float(e.y);
        float2 hr = *(const float2*)(h1 + (size_t)e.x * HID + 2 * c);
        ax = fmaf(hr.x, nrm, ax);
        ay = fmaf(hr.y, nrm, ay);
    }
    *(float2*)(out1 + (size_t)n * HID + 2 * c) =
        make_float2(fmaxf(ax, 0.0f), fmaxf(ay, 0.0f));
}

// h2 = out1 @ W2   (block = 256 = 4 waves; wave = 4 node-rows, lane = out channel)
// Row activations read at wave-uniform addresses -> scalar (SMEM) loads; W2 from LDS.
__global__ __launch_bounds__(256) void k_gemm2(
    const float* __restrict__ out1, const float* __restrict__ W2,
    float* __restrict__ h2, int N) {
    __shared__ float w2s[HID * OUTC];  // [k][c], 32 KiB
    for (int i = threadIdx.x; i < HID * OUTC; i += 256) w2s[i] = W2[i];
    __syncthreads();
    int c = threadIdx.x & 63;
    int g = threadIdx.x >> 6;
    long long base = (long long)blockIdx.x * 16 + g * 4;
    float acc0 = 0.f, acc1 = 0.f, acc2 = 0.f, acc3 = 0.f;
    long long n0 = (base + 0 < N) ? base + 0 : 0;
    long long n1 = (base + 1 < N) ? base + 1 : 0;
    long long n2 = (base + 2 < N) ? base + 2 : 0;
    long long n3 = (base + 3 < N) ? base + 3 : 0;
    const float* r0 = out1 + n0 * HID;
    const float* r1 = out1 + n1 * HID;
    const float* r2 = out1 + n2 * HID;
    const float* r3 = out1 + n3 * HID;
#pragma unroll
    for (int k0 = 0; k0 < HID; k0 += 16) {
        float a0[16], a1[16], a2[16], a3[16];
#pragma unroll
        for (int t = 0; t < 16; ++t) { a0[t] = r0[k0 + t]; a1[t] = r1[k0 + t];
                                       a2[t] = r2[k0 + t]; a3[t] = r3[k0 + t]; }
#pragma unroll
        for (int t = 0; t < 16; ++t) {
            float w = w2s[(k0 + t) * OUTC + c];
            acc0 = fmaf(a0[t], w, acc0);
            acc1 = fmaf(a1[t], w, acc1);
            acc2 = fmaf(a2[t], w, acc2);
            acc3 = fmaf(a3[t], w, acc3);
        }
    }
    if (base + 0 < N) h2[(base + 0) * OUTC + c] = acc0;
    if (base + 1 < N) h2[(base + 1) * OUTC + c] = acc1;
    if (base + 2 < N) h2[(base + 2) * OUTC + c] = acc2;
    if (base + 3 < N) h2[(base + 3) * OUTC + c] = acc3;
}

// out = sum h2[row]*norm + h2[n]*dinv^2 + b2   (wave = 1 node, lane = channel)
__global__ __launch_bounds__(256) void k_gather2(
    const int* __restrict__ start, const int* __restrict__ cnt,
    const float* __restrict__ dinv, const int2* __restrict__ edges,
    const float* __restrict__ h2, const float* __restrict__ b2,
    float* __restrict__ out, int N) {
    int ln = threadIdx.x >> 6;
    int c  = threadIdx.x & 63;
    int n  = blockIdx.x * 4 + ln;
    if (n >= N) return;
    float dv = dinv[n];
    float acc = fmaf(h2[(size_t)n * OUTC + c], dv * dv, b2[c]);
    int s0 = start[n], k = cnt[n];
#pragma unroll 4
    for (int j = 0; j < k; ++j) {
        int2 e = edges[s0 + j];
        acc = fmaf(h2[(size_t)e.x * OUTC + c], __int_as_float(e.y), acc);
    }
    out[(size_t)n * OUTC + c] = acc;
}

extern "C" void kernel_launch(void* const* d_in, const int* in_sizes, int n_in,
                              void* d_out, int out_size, void* d_ws, size_t ws_size,
                              hipStream_t stream) {
    const float* x  = (const float*)d_in[0];
    const int*   ei = (const int*)d_in[1];
    const float* W1 = (const float*)d_in[2];
    const float* b1 = (const float*)d_in[3];
    const float* W2 = (const float*)d_in[4];
    const float* b2 = (const float*)d_in[5];
    float* out = (float*)d_out;

    const int N = in_sizes[0] / IN_CH;
    const int E = in_sizes[1] / 2;
    const int* row = ei;
    const int* col = ei + E;

    // workspace layout (ints region contiguous so one zero-kernel covers cnt/cur/total)
    char* ws = (char*)d_ws;
    int*   cnt   = (int*)ws;                       // N
    int*   cur   = cnt + N;                        // N
    int*   total = cur + N;                        // 1 (cnt..total contiguous: 2N+1 ints)
    int*   start = total + 64;                     // N
    float* dinv  = (float*)(start + N + 64);       // N
    char*  p     = (char*)(dinv + N);
    p = (char*)(((uintptr_t)p + 255) & ~(uintptr_t)255);
    int2*  edges = (int2*)p;                       // E int2 (12.8 MB)
    float* h1    = (float*)(edges + E);            // N*128
    float* out1  = h1 + (size_t)N * HID;           // N*128
    float* h2    = h1;                             // alias (h1 dead after gather1)

    k_zero_i<<<(2 * N + 1 + 255) / 256, 256, 0, stream>>>(cnt, 2 * N + 1);
    k_count<<<(E + 255) / 256, 256, 0, stream>>>(col, cnt, E);
    k_alloc<<<(N + 255) / 256, 256, 0, stream>>>(cnt, dinv, start, total, N);
    k_fill<<<(E + 255) / 256, 256, 0, stream>>>(row, col, dinv, start, cur, edges, E);

    k_gemm1<<<(N + 1) / 2, 256, 0, stream>>>(x, W1, h1, N);
    k_gather1<<<(N + 3) / 4, 256, 0, stream>>>(start, cnt, dinv, edges, h1, b1, out1, N);
    k_gemm2<<<(N + 15) / 16, 256, 0, stream>>>(out1, W2, h2, N);
    k_gather2<<<(N + 3) / 4, 256, 0, stream>>>(start, cnt, dinv, edges, h2, b2, out, N);
}

// Round 3
// 424.524 us; speedup vs baseline: 2.9664x; 1.9422x over previous
//
#include <hip/hip_runtime.h>

// 2-layer GCN, CSR-gather formulation (no float atomics).
// Graph is shared by both layers: build dest-sorted CSR once, gather twice.

#define IN_CH 12
#define HID 128
#define OUTC 64
#define PADK 132  // 128 + 4 pad: row stride in floats for A tile (breaks pow2 bank stride)

__global__ void k_zero_i(int* __restrict__ p, int n) {
    int i = blockIdx.x * blockDim.x + threadIdx.x;
    if (i < n) p[i] = 0;
}

__global__ void k_count(const int* __restrict__ col, int* __restrict__ cnt, int E) {
    int e = blockIdx.x * blockDim.x + threadIdx.x;
    if (e < E) atomicAdd(&cnt[col[e]], 1);
}

// dinv[i] = rsqrt(cnt[i]+1); start[i] = running offset (block-scan + one atomic per block)
__global__ __launch_bounds__(256) void k_alloc(
    const int* __restrict__ cnt, float* __restrict__ dinv,
    int* __restrict__ start, int* __restrict__ total, int N) {
    __shared__ int sdata[256];
    __shared__ int sbase;
    int i = blockIdx.x * 256 + threadIdx.x;
    int v = (i < N) ? cnt[i] : 0;
    if (i < N) dinv[i] = rsqrtf((float)v + 1.0f);
    sdata[threadIdx.x] = v;
    __syncthreads();
#pragma unroll
    for (int off = 1; off < 256; off <<= 1) {
        int t = (threadIdx.x >= off) ? sdata[threadIdx.x - off] : 0;
        __syncthreads();
        sdata[threadIdx.x] += t;
        __syncthreads();
    }
    if (threadIdx.x == 255) sbase = atomicAdd(total, sdata[255]);
    __syncthreads();
    if (i < N) start[i] = sbase + sdata[threadIdx.x] - v;  // exclusive scan
}

// edges[start[col]+k] = {row, norm}  (norm precomputed once, reused by both layers)
__global__ void k_fill(const int* __restrict__ row, const int* __restrict__ col,
                       const float* __restrict__ dinv, const int* __restrict__ start,
                       int* __restrict__ cur, int2* __restrict__ edges, int E) {
    int e = blockIdx.x * blockDim.x + threadIdx.x;
    if (e >= E) return;
    int r = row[e], c = col[e];
    int p = start[c] + atomicAdd(&cur[c], 1);
    float nrm = dinv[r] * dinv[c];
    edges[p] = make_int2(r, __float_as_int(nrm));
}

// h1 = x @ W1   (block = 256 threads = 2 nodes x 128 ch)
__global__ __launch_bounds__(256) void k_gemm1(
    const float* __restrict__ x, const float* __restrict__ W1,
    float* __restrict__ h1, int N) {
    __shared__ float xs[2][IN_CH];
    int ln = threadIdx.x >> 7;
    int c  = threadIdx.x & 127;
    int n  = blockIdx.x * 2 + ln;
    if (threadIdx.x < 2 * IN_CH) {
        int nn = blockIdx.x * 2 + threadIdx.x / IN_CH;
        int k  = threadIdx.x % IN_CH;
        xs[threadIdx.x / IN_CH][k] = (nn < N) ? x[(long long)nn * IN_CH + k] : 0.0f;
    }
    __syncthreads();
    if (n >= N) return;
    float acc = 0.0f;
#pragma unroll
    for (int k = 0; k < IN_CH; ++k)
        acc = fmaf(xs[ln][k], W1[k * HID + c], acc);
    h1[(long long)n * HID + c] = acc;
}

// out1 = relu( sum_{e->n} h1[row_e]*norm_e + h1[n]*dinv^2 + b1 )
// block = 256 = 4 waves; wave = 1 node, lane = channel-pair (float2)
__global__ __launch_bounds__(256) void k_gather1(
    const int* __restrict__ start, const int* __restrict__ cnt,
    const float* __restrict__ dinv, const int2* __restrict__ edges,
    const float* __restrict__ h1, const float* __restrict__ b1,
    float* __restrict__ out1, int N) {
    int ln = threadIdx.x >> 6;
    int c  = threadIdx.x & 63;
    int n  = blockIdx.x * 4 + ln;
    if (n >= N) return;
    float dv = dinv[n];
    float2 hv = *(const float2*)(h1 + (size_t)n * HID + 2 * c);
    float2 bb = *(const float2*)(b1 + 2 * c);
    float s = dv * dv;
    float ax = fmaf(hv.x, s, bb.x);
    float ay = fmaf(hv.y, s, bb.y);
    int s0 = start[n], k = cnt[n];
#pragma unroll 4
    for (int j = 0; j < k; ++j) {
        int2 e = edges[s0 + j];                 // wave-uniform broadcast load
        float nrm = __int_as_float(e.y);
        float2 hr = *(const float2*)(h1 + (size_t)e.x * HID + 2 * c);
        ax = fmaf(hr.x, nrm, ax);
        ay = fmaf(hr.y, nrm, ay);
    }
    *(float2*)(out1 + (size_t)n * HID + 2 * c) =
        make_float2(fmaxf(ax, 0.0f), fmaxf(ay, 0.0f));
}

// h2 = out1 @ W2 : LDS-tiled GEMM. Block = 64 rows x 64 cols, 256 threads,
// each thread a 4x4 register tile, float4 LDS reads both operands.
__global__ __launch_bounds__(256) void k_gemm2(
    const float* __restrict__ out1, const float* __restrict__ W2,
    float* __restrict__ h2, int N) {
    __shared__ float as[64 * PADK];   // A tile, row-major, padded (33.8 KiB)
    __shared__ float ws[HID * OUTC];  // W2 [k][c] (32 KiB)
    for (int i = threadIdx.x; i < (HID * OUTC) / 4; i += 256)
        ((float4*)ws)[i] = ((const float4*)W2)[i];
    long long base = (long long)blockIdx.x * 64;
    // stage A: 64 rows x 128 cols = 2048 float4, coalesced
    for (int i = threadIdx.x; i < 2048; i += 256) {
        int r = i >> 5, kq = i & 31;  // 32 float4 per row
        long long rr = base + r; if (rr >= N) rr = N - 1;
        float4 v = ((const float4*)(out1 + rr * HID))[kq];
        *(float4*)(as + r * PADK + 4 * kq) = v;
    }
    __syncthreads();
    int tc = threadIdx.x & 15;   // col group: cols 4*tc..4*tc+3
    int tr = threadIdx.x >> 4;   // row group: rows 4*tr..4*tr+3
    float acc[4][4] = {};
    const float* ar = as + 4 * tr * PADK;
#pragma unroll 8
    for (int k = 0; k < HID; k += 4) {
        float4 a[4], w[4];
#pragma unroll
        for (int j = 0; j < 4; ++j) a[j] = *(const float4*)(ar + j * PADK + k);
#pragma unroll
        for (int kk = 0; kk < 4; ++kk) w[kk] = *(const float4*)(ws + (k + kk) * OUTC + 4 * tc);
#pragma unroll
        for (int kk = 0; kk < 4; ++kk) {
            float aw[4] = {w[kk].x, w[kk].y, w[kk].z, w[kk].w};
#pragma unroll
            for (int j = 0; j < 4; ++j) {
                float av = (kk == 0) ? a[j].x : (kk == 1) ? a[j].y : (kk == 2) ? a[j].z : a[j].w;
                acc[j][0] = fmaf(av, aw[0], acc[j][0]);
                acc[j][1] = fmaf(av, aw[1], acc[j][1]);
                acc[j][2] = fmaf(av, aw[2], acc[j][2]);
                acc[j][3] = fmaf(av, aw[3], acc[j][3]);
            }
        }
    }
#pragma unroll
    for (int j = 0; j < 4; ++j) {
        long long r = base + 4 * tr + j;
        if (r < N)
            *(float4*)(h2 + r * OUTC + 4 * tc) =
                make_float4(acc[j][0], acc[j][1], acc[j][2], acc[j][3]);
    }
}

// out = sum h2[row]*norm + h2[n]*dinv^2 + b2   (wave = 1 node, lane = channel)
__global__ __launch_bounds__(256) void k_gather2(
    const int* __restrict__ start, const int* __restrict__ cnt,
    const float* __restrict__ dinv, const int2* __restrict__ edges,
    const float* __restrict__ h2, const float* __restrict__ b2,
    float* __restrict__ out, int N) {
    int ln = threadIdx.x >> 6;
    int c  = threadIdx.x & 63;
    int n  = blockIdx.x * 4 + ln;
    if (n >= N) return;
    float dv = dinv[n];
    float acc = fmaf(h2[(size_t)n * OUTC + c], dv * dv, b2[c]);
    int s0 = start[n], k = cnt[n];
#pragma unroll 4
    for (int j = 0; j < k; ++j) {
        int2 e = edges[s0 + j];
        acc = fmaf(h2[(size_t)e.x * OUTC + c], __int_as_float(e.y), acc);
    }
    out[(size_t)n * OUTC + c] = acc;
}

extern "C" void kernel_launch(void* const* d_in, const int* in_sizes, int n_in,
                              void* d_out, int out_size, void* d_ws, size_t ws_size,
                              hipStream_t stream) {
    const float* x  = (const float*)d_in[0];
    const int*   ei = (const int*)d_in[1];
    const float* W1 = (const float*)d_in[2];
    const float* b1 = (const float*)d_in[3];
    const float* W2 = (const float*)d_in[4];
    const float* b2 = (const float*)d_in[5];
    float* out = (float*)d_out;

    const int N = in_sizes[0] / IN_CH;
    const int E = in_sizes[1] / 2;
    const int* row = ei;
    const int* col = ei + E;

    // workspace layout (ints region contiguous so one zero-kernel covers cnt/cur/total)
    char* ws = (char*)d_ws;
    int*   cnt   = (int*)ws;                       // N
    int*   cur   = cnt + N;                        // N
    int*   total = cur + N;                        // 1 (cnt..total contiguous: 2N+1 ints)
    int*   start = total + 64;                     // N
    float* dinv  = (float*)(start + N + 64);       // N
    char*  p     = (char*)(dinv + N);
    p = (char*)(((uintptr_t)p + 255) & ~(uintptr_t)255);
    int2*  edges = (int2*)p;                       // E int2 (12.8 MB)
    float* h1    = (float*)(edges + E);            // N*128
    float* out1  = h1 + (size_t)N * HID;           // N*128
    float* h2    = h1;                             // alias (h1 dead after gather1)

    k_zero_i<<<(2 * N + 1 + 255) / 256, 256, 0, stream>>>(cnt, 2 * N + 1);
    k_count<<<(E + 255) / 256, 256, 0, stream>>>(col, cnt, E);
    k_alloc<<<(N + 255) / 256, 256, 0, stream>>>(cnt, dinv, start, total, N);
    k_fill<<<(E + 255) / 256, 256, 0, stream>>>(row, col, dinv, start, cur, edges, E);

    k_gemm1<<<(N + 1) / 2, 256, 0, stream>>>(x, W1, h1, N);
    k_gather1<<<(N + 3) / 4, 256, 0, stream>>>(start, cnt, dinv, edges, h1, b1, out1, N);
    k_gemm2<<<(N + 63) / 64, 256, 0, stream>>>(out1, W2, h2, N);
    k_gather2<<<(N + 3) / 4, 256, 0, stream>>>(start, cnt, dinv, edges, h2, b2, out, N);
}

// Round 4
// 323.839 us; speedup vs baseline: 3.8886x; 1.3109x over previous
//
#include <hip/hip_runtime.h>

// 2-layer GCN, CSR-gather formulation (no float atomics).
// Key identity: A_norm·(x@W1) = (A_norm·x)@W1 -> aggregate layer 1 in 12-ch space.
// Graph shared by both layers: build dest-sorted CSR once, gather twice.

#define IN_CH 12
#define HID 128
#define OUTC 64
#define PADK 132  // A-tile row stride in floats for gemm2 (breaks pow2 bank stride)

__global__ void k_zero_i(int* __restrict__ p, int n) {
    int i = blockIdx.x * blockDim.x + threadIdx.x;
    if (i < n) p[i] = 0;
}

__global__ void k_count(const int* __restrict__ col, int* __restrict__ cnt, int E) {
    int e = blockIdx.x * blockDim.x + threadIdx.x;
    if (e < E) atomicAdd(&cnt[col[e]], 1);
}

// dinv[i] = rsqrt(cnt[i]+1); start[i] = running offset (block-scan + one atomic per block)
__global__ __launch_bounds__(256) void k_alloc(
    const int* __restrict__ cnt, float* __restrict__ dinv,
    int* __restrict__ start, int* __restrict__ total, int N) {
    __shared__ int sdata[256];
    __shared__ int sbase;
    int i = blockIdx.x * 256 + threadIdx.x;
    int v = (i < N) ? cnt[i] : 0;
    if (i < N) dinv[i] = rsqrtf((float)v + 1.0f);
    sdata[threadIdx.x] = v;
    __syncthreads();
#pragma unroll
    for (int off = 1; off < 256; off <<= 1) {
        int t = (threadIdx.x >= off) ? sdata[threadIdx.x - off] : 0;
        __syncthreads();
        sdata[threadIdx.x] += t;
        __syncthreads();
    }
    if (threadIdx.x == 255) sbase = atomicAdd(total, sdata[255]);
    __syncthreads();
    if (i < N) start[i] = sbase + sdata[threadIdx.x] - v;  // exclusive scan
}

// edges[start[col]+k] = {row, norm}  (norm precomputed once, reused by both layers)
__global__ void k_fill(const int* __restrict__ row, const int* __restrict__ col,
                       const float* __restrict__ dinv, const int* __restrict__ start,
                       int* __restrict__ cur, int2* __restrict__ edges, int E) {
    int e = blockIdx.x * blockDim.x + threadIdx.x;
    if (e >= E) return;
    int r = row[e], c = col[e];
    int p = start[c] + atomicAdd(&cur[c], 1);
    float nrm = dinv[r] * dinv[c];
    edges[p] = make_int2(r, __float_as_int(nrm));
}

// aggx[n] = sum_{e->n} x[row_e]*norm_e + x[n]*dinv^2   (12 channels)
// block = 192 threads = 16 nodes x 12 lanes; edge load broadcast per lane-group,
// x row = 48 contiguous bytes across the 12 lanes.
__global__ __launch_bounds__(192) void k_gather_x(
    const int* __restrict__ start, const int* __restrict__ cnt,
    const float* __restrict__ dinv, const int2* __restrict__ edges,
    const float* __restrict__ x, float* __restrict__ aggx, int N) {
    int ln = threadIdx.x / 12;
    int c  = threadIdx.x % 12;
    int n  = blockIdx.x * 16 + ln;
    if (n >= N) return;
    float dv = dinv[n];
    float acc = x[(size_t)n * IN_CH + c] * dv * dv;
    int s0 = start[n], k = cnt[n];
#pragma unroll 4
    for (int j = 0; j < k; ++j) {
        int2 e = edges[s0 + j];
        acc = fmaf(x[(size_t)e.x * IN_CH + c], __int_as_float(e.y), acc);
    }
    aggx[(size_t)n * IN_CH + c] = acc;
}

// out1 = relu(aggx @ W1 + b1)   (block = 256 threads, 16 nodes x 128 ch)
__global__ __launch_bounds__(256) void k_gemm1b(
    const float* __restrict__ aggx, const float* __restrict__ W1,
    const float* __restrict__ b1, float* __restrict__ out1, int N) {
    __shared__ float w1s[IN_CH * HID];  // 6 KiB
    __shared__ float axs[16][IN_CH];    // 768 B
    for (int i = threadIdx.x; i < IN_CH * HID; i += 256) w1s[i] = W1[i];
    long long base = (long long)blockIdx.x * 16;
    if (threadIdx.x < 16 * IN_CH) {
        int r = threadIdx.x / IN_CH, k = threadIdx.x % IN_CH;
        long long n = base + r;
        axs[r][k] = (n < N) ? aggx[n * IN_CH + k] : 0.0f;
    }
    __syncthreads();
    int c    = threadIdx.x & 127;
    int half = threadIdx.x >> 7;  // 0..1 -> nodes half*8 .. half*8+7
    float bb = b1[c];
    float acc[8];
#pragma unroll
    for (int j = 0; j < 8; ++j) acc[j] = bb;
#pragma unroll
    for (int k = 0; k < IN_CH; ++k) {
        float w = w1s[k * HID + c];
#pragma unroll
        for (int j = 0; j < 8; ++j)
            acc[j] = fmaf(axs[half * 8 + j][k], w, acc[j]);
    }
#pragma unroll
    for (int j = 0; j < 8; ++j) {
        long long n = base + half * 8 + j;
        if (n < N) out1[n * HID + c] = fmaxf(acc[j], 0.0f);
    }
}

// h2 = out1 @ W2 : LDS-tiled GEMM. Block = 64 rows x 64 cols, 256 threads,
// each thread a 4x4 register tile, float4 LDS reads both operands.
__global__ __launch_bounds__(256) void k_gemm2(
    const float* __restrict__ out1, const float* __restrict__ W2,
    float* __restrict__ h2, int N) {
    __shared__ float as[64 * PADK];   // A tile, row-major, padded (33.8 KiB)
    __shared__ float ws[HID * OUTC];  // W2 [k][c] (32 KiB)
    for (int i = threadIdx.x; i < (HID * OUTC) / 4; i += 256)
        ((float4*)ws)[i] = ((const float4*)W2)[i];
    long long base = (long long)blockIdx.x * 64;
    for (int i = threadIdx.x; i < 2048; i += 256) {
        int r = i >> 5, kq = i & 31;
        long long rr = base + r; if (rr >= N) rr = N - 1;
        float4 v = ((const float4*)(out1 + rr * HID))[kq];
        *(float4*)(as + r * PADK + 4 * kq) = v;
    }
    __syncthreads();
    int tc = threadIdx.x & 15;
    int tr = threadIdx.x >> 4;
    float acc[4][4] = {};
    const float* ar = as + 4 * tr * PADK;
#pragma unroll 8
    for (int k = 0; k < HID; k += 4) {
        float4 a[4], w[4];
#pragma unroll
        for (int j = 0; j < 4; ++j) a[j] = *(const float4*)(ar + j * PADK + k);
#pragma unroll
        for (int kk = 0; kk < 4; ++kk) w[kk] = *(const float4*)(ws + (k + kk) * OUTC + 4 * tc);
#pragma unroll
        for (int kk = 0; kk < 4; ++kk) {
            float aw[4] = {w[kk].x, w[kk].y, w[kk].z, w[kk].w};
#pragma unroll
            for (int j = 0; j < 4; ++j) {
                float av = (kk == 0) ? a[j].x : (kk == 1) ? a[j].y : (kk == 2) ? a[j].z : a[j].w;
                acc[j][0] = fmaf(av, aw[0], acc[j][0]);
                acc[j][1] = fmaf(av, aw[1], acc[j][1]);
                acc[j][2] = fmaf(av, aw[2], acc[j][2]);
                acc[j][3] = fmaf(av, aw[3], acc[j][3]);
            }
        }
    }
#pragma unroll
    for (int j = 0; j < 4; ++j) {
        long long r = base + 4 * tr + j;
        if (r < N)
            *(float4*)(h2 + r * OUTC + 4 * tc) =
                make_float4(acc[j][0], acc[j][1], acc[j][2], acc[j][3]);
    }
}

// out = sum h2[row]*norm + h2[n]*dinv^2 + b2   (wave = 1 node, lane = channel)
__global__ __launch_bounds__(256) void k_gather2(
    const int* __restrict__ start, const int* __restrict__ cnt,
    const float* __restrict__ dinv, const int2* __restrict__ edges,
    const float* __restrict__ h2, const float* __restrict__ b2,
    float* __restrict__ out, int N) {
    int ln = threadIdx.x >> 6;
    int c  = threadIdx.x & 63;
    int n  = blockIdx.x * 4 + ln;
    if (n >= N) return;
    float dv = dinv[n];
    float acc = fmaf(h2[(size_t)n * OUTC + c], dv * dv, b2[c]);
    int s0 = start[n], k = cnt[n];
#pragma unroll 4
    for (int j = 0; j < k; ++j) {
        int2 e = edges[s0 + j];
        acc = fmaf(h2[(size_t)e.x * OUTC + c], __int_as_float(e.y), acc);
    }
    out[(size_t)n * OUTC + c] = acc;
}

extern "C" void kernel_launch(void* const* d_in, const int* in_sizes, int n_in,
                              void* d_out, int out_size, void* d_ws, size_t ws_size,
                              hipStream_t stream) {
    const float* x  = (const float*)d_in[0];
    const int*   ei = (const int*)d_in[1];
    const float* W1 = (const float*)d_in[2];
    const float* b1 = (const float*)d_in[3];
    const float* W2 = (const float*)d_in[4];
    const float* b2 = (const float*)d_in[5];
    float* out = (float*)d_out;

    const int N = in_sizes[0] / IN_CH;
    const int E = in_sizes[1] / 2;
    const int* row = ei;
    const int* col = ei + E;

    char* ws = (char*)d_ws;
    int*   cnt   = (int*)ws;                       // N
    int*   cur   = cnt + N;                        // N
    int*   total = cur + N;                        // 1 (cnt..total contiguous: 2N+1 ints)
    int*   start = total + 64;                     // N
    float* dinv  = (float*)(start + N + 64);       // N
    char*  p     = (char*)(dinv + N);
    p = (char*)(((uintptr_t)p + 255) & ~(uintptr_t)255);
    int2*  edges = (int2*)p;                       // E int2 (12.8 MB)
    float* aggx  = (float*)(edges + E);            // N*12
    float* out1  = aggx + (size_t)N * IN_CH;       // N*128
    float* h2    = out1 + (size_t)N * HID;         // N*64

    k_zero_i<<<(2 * N + 1 + 255) / 256, 256, 0, stream>>>(cnt, 2 * N + 1);
    k_count<<<(E + 255) / 256, 256, 0, stream>>>(col, cnt, E);
    k_alloc<<<(N + 255) / 256, 256, 0, stream>>>(cnt, dinv, start, total, N);
    k_fill<<<(E + 255) / 256, 256, 0, stream>>>(row, col, dinv, start, cur, edges, E);

    k_gather_x<<<(N + 15) / 16, 192, 0, stream>>>(start, cnt, dinv, edges, x, aggx, N);
    k_gemm1b<<<(N + 15) / 16, 256, 0, stream>>>(aggx, W1, b1, out1, N);
    k_gemm2<<<(N + 63) / 64, 256, 0, stream>>>(out1, W2, h2, N);
    k_gather2<<<(N + 3) / 4, 256, 0, stream>>>(start, cnt, dinv, edges, h2, b2, out, N);
}